// Round 1
// 453.524 us; speedup vs baseline: 1.0754x; 1.0754x over previous
//
#include <hip/hip_runtime.h>
#include <hip/hip_bf16.h>

#define N_NODES 100000
#define N_EDGES 1600000
#define IN_DIM  128
#define HID     64
#define BIN_NODES 256
#define NBINS   ((N_NODES + BIN_NODES - 1) / BIN_NODES)   // 391
#define EB      2048       // edges per block in bin_hist / bin_scatter

#define PITCH_IN  152      // bf16 units per LDS row for K=128 (+24 pad: 2-way banks, 16B-aligned)
#define PITCH_HID 88       // bf16 units per LDS row for K=64  (+24 pad)

typedef __attribute__((ext_vector_type(8))) short bf16x8;   // MFMA A/B frag (4 VGPRs)
typedef __attribute__((ext_vector_type(4))) float f32x4;    // MFMA C/D frag

__device__ inline unsigned short f2bf(float f) {
    __hip_bfloat16 b = __float2bfloat16(f);
    return *reinterpret_cast<unsigned short*>(&b);
}

// ---------------------------------------------------------------------------
// Pre-pack W matrices into B-fragment order bf16:
// flat = (((kc*4 + nt)*4 + quad)*16 + n16)*8 + j ;  k = kc*32+quad*8+j, n = nt*16+n16
// ---------------------------------------------------------------------------
__global__ void wf_prep_kernel(const float* __restrict__ Wi,
                               const float* __restrict__ W1,
                               const float* __restrict__ W2,
                               const float* __restrict__ W3,
                               unsigned short* __restrict__ wf_in,
                               unsigned short* __restrict__ wf_hid) {
    int t = blockIdx.x * 256 + threadIdx.x;
    if (t < 8192) {  // Wi: K=128 -> kc in 0..3
        int j = t & 7, n16 = (t >> 3) & 15, quad = (t >> 7) & 3, nt = (t >> 9) & 3, kc = t >> 11;
        int k = kc * 32 + quad * 8 + j, n = nt * 16 + n16;
        wf_in[t] = f2bf(Wi[k * HID + n]);
    }
    if (t < 4096) {  // W1..W3: K=64 -> kc in 0..1
        int j = t & 7, n16 = (t >> 3) & 15, quad = (t >> 7) & 3, nt = (t >> 9) & 3, kc = t >> 11;
        int k = kc * 32 + quad * 8 + j, n = nt * 16 + n16;
        wf_hid[t]        = f2bf(W1[k * HID + n]);
        wf_hid[4096 + t] = f2bf(W2[k * HID + n]);
        wf_hid[8192 + t] = f2bf(W3[k * HID + n]);
    }
}

// ---------------------------------------------------------------------------
// h0 = relu(x @ Wi + bi) via bf16 MFMA. Block = 64 rows, wave = 16 rows.
// ---------------------------------------------------------------------------
__global__ __launch_bounds__(256) void gemm_in_kernel(
        const float* __restrict__ x,
        const unsigned short* __restrict__ wf,   // fragment-order Wi (bf16 bits)
        const float* __restrict__ bi,
        float* __restrict__ h0,
        __hip_bfloat16* __restrict__ hbf) {
    __shared__ unsigned short sX[64 * PITCH_IN];   // 19456 B
    const int tid  = threadIdx.x;
    const int row0 = blockIdx.x * 64;

    // Stage x tile (64 x 128 f32 -> bf16), coalesced float4 reads, 8B LDS writes.
    #pragma unroll
    for (int it = 0; it < 8; ++it) {
        int i  = tid + it * 256;
        int r  = i >> 5;        // 32 float4 per row
        int kq = i & 31;
        int rg = row0 + r;
        float4 v = (rg < N_NODES)
                 ? ((const float4*)x)[(size_t)rg * (IN_DIM / 4) + kq]
                 : make_float4(0.f, 0.f, 0.f, 0.f);
        ushort4 pk;
        pk.x = f2bf(v.x); pk.y = f2bf(v.y); pk.z = f2bf(v.z); pk.w = f2bf(v.w);
        *(ushort4*)(sX + r * PITCH_IN + kq * 4) = pk;
    }
    __syncthreads();

    const int lane = tid & 63;
    const int wid  = tid >> 6;
    const int l16  = lane & 15;
    const int q    = lane >> 4;

    f32x4 acc[4] = {{0,0,0,0},{0,0,0,0},{0,0,0,0},{0,0,0,0}};
    const bf16x8* wf8 = (const bf16x8*)wf;

    #pragma unroll
    for (int kc = 0; kc < 4; ++kc) {
        bf16x8 af = *(const bf16x8*)(sX + (wid * 16 + l16) * PITCH_IN + kc * 32 + q * 8);
        #pragma unroll
        for (int nt = 0; nt < 4; ++nt) {
            bf16x8 bfr = wf8[((kc * 4 + nt) * 4 + q) * 16 + l16];
            acc[nt] = __builtin_amdgcn_mfma_f32_16x16x32_bf16(af, bfr, acc[nt], 0, 0, 0);
        }
    }

    // Epilogue: C/D layout col = lane&15, row = quad*4 + reg  [m89]
    #pragma unroll
    for (int nt = 0; nt < 4; ++nt) {
        float bb = bi[nt * 16 + l16];
        #pragma unroll
        for (int reg = 0; reg < 4; ++reg) {
            int rg = row0 + wid * 16 + q * 4 + reg;
            if (rg < N_NODES) {
                float v = fmaxf(acc[nt][reg] + bb, 0.0f);
                h0 [(size_t)rg * HID + nt * 16 + l16] = v;
                hbf[(size_t)rg * HID + nt * 16 + l16] = __float2bfloat16(v);
            }
        }
    }
}

// ---------------------------------------------------------------------------
// Binned CSR build.  Record: high32 = w bits, low32 = (local_tgt<<17) | src.
// ---------------------------------------------------------------------------
__global__ void bin_hist_kernel(const int* __restrict__ tgt,
                                int* __restrict__ g_bin_cnt) {
    __shared__ int cnt[NBINS];
    for (int i = threadIdx.x; i < NBINS; i += 256) cnt[i] = 0;
    __syncthreads();
    const int e0 = blockIdx.x * EB;
    for (int i = threadIdx.x; i < EB; i += 256) {
        int e = e0 + i;
        if (e < N_EDGES) atomicAdd(&cnt[tgt[e] >> 8], 1);
    }
    __syncthreads();
    for (int i = threadIdx.x; i < NBINS; i += 256)
        if (cnt[i]) atomicAdd(&g_bin_cnt[i], cnt[i]);
}

__global__ void bin_scan_kernel(const int* __restrict__ g_bin_cnt,
                                int* __restrict__ g_bin_offs,
                                int* __restrict__ g_bin_cursor) {
    __shared__ int s[512];
    const int tid = threadIdx.x;
    int v = (tid < NBINS) ? g_bin_cnt[tid] : 0;
    s[tid] = v;
    __syncthreads();
    for (int off = 1; off < 512; off <<= 1) {
        int t = (tid >= off) ? s[tid - off] : 0;
        __syncthreads();
        s[tid] += t;
        __syncthreads();
    }
    if (tid < NBINS) { g_bin_offs[tid] = s[tid] - v; g_bin_cursor[tid] = s[tid] - v; }
}

__global__ void bin_scatter_kernel(const int* __restrict__ src,
                                   const int* __restrict__ tgt,
                                   const float* __restrict__ ea,
                                   int* __restrict__ g_bin_cursor,
                                   unsigned long long* __restrict__ binned) {
    __shared__ int cnt[NBINS];
    __shared__ int base[NBINS];
    __shared__ int cur[NBINS];
    for (int i = threadIdx.x; i < NBINS; i += 256) cnt[i] = 0;
    __syncthreads();

    const int e0 = blockIdx.x * EB;
    int myb[EB / 256];
    unsigned long long myrec[EB / 256];
    #pragma unroll
    for (int i = 0; i < EB / 256; ++i) {
        int e = e0 + threadIdx.x + i * 256;
        if (e < N_EDGES) {
            int t = tgt[e];
            int b = t >> 8;
            myb[i] = b;
            myrec[i] = ((unsigned long long)(unsigned)__float_as_int(ea[e]) << 32)
                     | ((unsigned)(t & 255) << 17) | (unsigned)src[e];
            atomicAdd(&cnt[b], 1);
        } else {
            myb[i] = -1;
        }
    }
    __syncthreads();
    for (int i = threadIdx.x; i < NBINS; i += 256) {
        cur[i]  = 0;
        base[i] = cnt[i] ? atomicAdd(&g_bin_cursor[i], cnt[i]) : 0;
    }
    __syncthreads();
    #pragma unroll
    for (int i = 0; i < EB / 256; ++i) {
        if (myb[i] >= 0) {
            int r = atomicAdd(&cur[myb[i]], 1);
            binned[base[myb[i]] + r] = myrec[i];
        }
    }
}

__global__ void fine_fill_kernel(const unsigned long long* __restrict__ binned,
                                 const int* __restrict__ g_bin_offs,
                                 const int* __restrict__ g_bin_cnt,
                                 int* __restrict__ offs,
                                 int* __restrict__ counts,
                                 unsigned long long* __restrict__ pairs) {
    __shared__ int ncnt[256];
    __shared__ int nbase[256];
    __shared__ int wsum[4];
    const int b    = blockIdx.x;
    const int tid  = threadIdx.x;
    const int ebeg = g_bin_offs[b];
    const int ecnt = g_bin_cnt[b];

    ncnt[tid] = 0;
    __syncthreads();
    for (int i = tid; i < ecnt; i += 256) {
        int lt = (int)((binned[ebeg + i] >> 17) & 255);
        atomicAdd(&ncnt[lt], 1);
    }
    __syncthreads();

    const int lane = tid & 63, wid = tid >> 6;
    int v  = ncnt[tid];
    int sc = v;
    #pragma unroll
    for (int d = 1; d < 64; d <<= 1) {
        int t = __shfl_up(sc, d);
        if (lane >= d) sc += t;
    }
    if (lane == 63) wsum[wid] = sc;
    __syncthreads();
    int wb = 0;
    for (int w = 0; w < wid; ++w) wb += wsum[w];
    int excl = wb + sc - v;
    nbase[tid] = excl;

    const int node = b * BIN_NODES + tid;
    if (node < N_NODES) { offs[node] = ebeg + excl; counts[node] = v; }

    ncnt[tid] = 0;  // reuse as cursor
    __syncthreads();
    for (int i = tid; i < ecnt; i += 256) {
        unsigned long long rec = binned[ebeg + i];
        int lt = (int)((rec >> 17) & 255);
        int r  = atomicAdd(&ncnt[lt], 1);
        pairs[ebeg + nbase[lt] + r] =
            (rec & 0xFFFFFFFF00000000ull) | (rec & 0x1FFFFull);
    }
}

// ---------------------------------------------------------------------------
// FUSED: a = h + segment_sum(bf16(h)[src] * w) ; hnext = relu(a @ W + b).
// Block = 64 nodes = one MFMA tile. Phase 1: each wave aggregates 16 nodes
// (4 edges in flight x 16 lanes x 4 cols), result converted to bf16 straight
// into the MFMA staging LDS (no tmp round-trip through HBM). Phase 2: the
// 16x16x32 MFMA + relu epilogue of the old gemm_hid.
// hbf is double-buffered across layers: phase 2 writes layer l+1 rows while
// other blocks' phase 1 still gathers layer-l rows from arbitrary nodes.
// ---------------------------------------------------------------------------
__global__ __launch_bounds__(256) void agg_gemm_kernel(
        const float* __restrict__ h,               // layer-l activations (f32)
        const __hip_bfloat16* __restrict__ hbf_in, // layer-l activations (bf16)
        const int* __restrict__ offs,
        const int* __restrict__ counts,
        const int2* __restrict__ pairs,
        const unsigned short* __restrict__ wf,     // fragment-order W (bf16 bits)
        const float* __restrict__ b,
        float* __restrict__ hnext,
        __hip_bfloat16* __restrict__ hbf_out) {
    __shared__ unsigned short sX[64 * PITCH_HID];  // 11264 B
    const int tid  = threadIdx.x;
    const int row0 = blockIdx.x * 64;
    const int lane = tid & 63;
    const int wid  = tid >> 6;
    const int grp  = lane >> 4;
    const int sub  = lane & 15;

    // ---- Phase 1: aggregate 16 nodes per wave into LDS (bf16) ----
    for (int t = 0; t < 16; ++t) {
        const int node = row0 + wid * 16 + t;      // wave-uniform
        if (node < N_NODES) {
            const int beg = offs[node];
            const int cnt = counts[node];
            float ax = 0.f, ay = 0.f, az = 0.f, aw = 0.f;
            if (cnt > 0) {
                const int last = cnt - 1;
                for (int i = 0; i < cnt; i += 8) {
                    int e0 = i + grp;
                    int e1 = i + 4 + grp;
                    bool l0 = (e0 <= last);
                    bool l1 = (e1 <= last);
                    int2 p0 = pairs[beg + (l0 ? e0 : last)];
                    int2 p1 = pairs[beg + (l1 ? e1 : last)];
                    uint2 g0 = *(const uint2*)(hbf_in + (size_t)p0.x * HID + sub * 4);
                    uint2 g1 = *(const uint2*)(hbf_in + (size_t)p1.x * HID + sub * 4);
                    float w0 = l0 ? __int_as_float(p0.y) : 0.0f;
                    float w1 = l1 ? __int_as_float(p1.y) : 0.0f;
                    ax += w0 * __uint_as_float(g0.x << 16);
                    ay += w0 * __uint_as_float(g0.x & 0xFFFF0000u);
                    az += w0 * __uint_as_float(g0.y << 16);
                    aw += w0 * __uint_as_float(g0.y & 0xFFFF0000u);
                    ax += w1 * __uint_as_float(g1.x << 16);
                    ay += w1 * __uint_as_float(g1.x & 0xFFFF0000u);
                    az += w1 * __uint_as_float(g1.y << 16);
                    aw += w1 * __uint_as_float(g1.y & 0xFFFF0000u);
                }
            }
            ax += __shfl_xor(ax, 16); ay += __shfl_xor(ay, 16);
            az += __shfl_xor(az, 16); aw += __shfl_xor(aw, 16);
            ax += __shfl_xor(ax, 32); ay += __shfl_xor(ay, 32);
            az += __shfl_xor(az, 32); aw += __shfl_xor(aw, 32);
            if (grp == 0) {
                const float4 hv = *(const float4*)(h + (size_t)node * HID + sub * 4);
                ushort4 pk;
                pk.x = f2bf(hv.x + ax); pk.y = f2bf(hv.y + ay);
                pk.z = f2bf(hv.z + az); pk.w = f2bf(hv.w + aw);
                *(ushort4*)(sX + (wid * 16 + t) * PITCH_HID + sub * 4) = pk;
            }
        } else if (grp == 0) {
            ushort4 z; z.x = 0; z.y = 0; z.z = 0; z.w = 0;
            *(ushort4*)(sX + (wid * 16 + t) * PITCH_HID + sub * 4) = z;
        }
    }
    __syncthreads();

    // ---- Phase 2: 16x16x32 bf16 MFMA (K=64) + relu epilogue ----
    const int l16 = lane & 15;
    const int q   = lane >> 4;

    f32x4 acc[4] = {{0,0,0,0},{0,0,0,0},{0,0,0,0},{0,0,0,0}};
    const bf16x8* wf8 = (const bf16x8*)wf;

    #pragma unroll
    for (int kc = 0; kc < 2; ++kc) {
        bf16x8 af = *(const bf16x8*)(sX + (wid * 16 + l16) * PITCH_HID + kc * 32 + q * 8);
        #pragma unroll
        for (int nt = 0; nt < 4; ++nt) {
            bf16x8 bfr = wf8[((kc * 4 + nt) * 4 + q) * 16 + l16];
            acc[nt] = __builtin_amdgcn_mfma_f32_16x16x32_bf16(af, bfr, acc[nt], 0, 0, 0);
        }
    }

    #pragma unroll
    for (int nt = 0; nt < 4; ++nt) {
        float bb = b[nt * 16 + l16];
        #pragma unroll
        for (int reg = 0; reg < 4; ++reg) {
            int rg = row0 + wid * 16 + q * 4 + reg;
            if (rg < N_NODES) {
                float v = fmaxf(acc[nt][reg] + bb, 0.0f);
                hnext  [(size_t)rg * HID + nt * 16 + l16] = v;
                hbf_out[(size_t)rg * HID + nt * 16 + l16] = __float2bfloat16(v);
            }
        }
    }
}

extern "C" void kernel_launch(void* const* d_in, const int* in_sizes, int n_in,
                              void* d_out, int out_size, void* d_ws, size_t ws_size,
                              hipStream_t stream) {
    const float* x   = (const float*)d_in[0];
    const int*   ei  = (const int*)  d_in[1];   // (2, E): [src | tgt]
    const float* ea  = (const float*)d_in[2];
    const float* Wi  = (const float*)d_in[3];
    const float* bi  = (const float*)d_in[4];
    const float* W1  = (const float*)d_in[5];
    const float* b1  = (const float*)d_in[6];
    const float* W2  = (const float*)d_in[7];
    const float* b2  = (const float*)d_in[8];
    const float* W3  = (const float*)d_in[9];
    const float* b3  = (const float*)d_in[10];
    const float* bl[3] = { b1, b2, b3 };
    float* out = (float*)d_out;  // (4, N, HID)

    const int* src = ei;
    const int* tgt = ei + N_EDGES;

    // Workspace layout (no tmp buffer anymore; hbf double-buffered).
    unsigned long long* binned = (unsigned long long*)d_ws;          // E * 8B
    int* offs         = (int*)(binned + N_EDGES);
    int* counts       = offs + N_NODES;
    int* g_bin_cnt    = counts + N_NODES;
    int* g_bin_offs   = g_bin_cnt + NBINS;
    int* g_bin_cursor = g_bin_offs + NBINS;
    int* pad          = g_bin_cursor + NBINS;                        // keep 8B align
    unsigned long long* pairs = (unsigned long long*)(pad + 1);      // E * 8B
    __hip_bfloat16* hbf0 = (__hip_bfloat16*)(pairs + N_EDGES);       // N*HID bf16
    __hip_bfloat16* hbf1 = hbf0 + (size_t)N_NODES * HID;             // N*HID bf16
    unsigned short* wf_in  = (unsigned short*)(hbf1 + (size_t)N_NODES * HID);
    unsigned short* wf_hid = wf_in + 8192;                           // 3 x 4096

    hipMemsetAsync(g_bin_cnt, 0, NBINS * sizeof(int), stream);

    wf_prep_kernel<<<32, 256, 0, stream>>>(Wi, W1, W2, W3, wf_in, wf_hid);

    const int eb_blocks = (N_EDGES + EB - 1) / EB;  // 782
    bin_hist_kernel   <<<eb_blocks, 256, 0, stream>>>(tgt, g_bin_cnt);
    bin_scan_kernel   <<<1, 512, 0, stream>>>(g_bin_cnt, g_bin_offs, g_bin_cursor);
    bin_scatter_kernel<<<eb_blocks, 256, 0, stream>>>(src, tgt, ea, g_bin_cursor, binned);
    fine_fill_kernel  <<<NBINS, 256, 0, stream>>>(binned, g_bin_offs, g_bin_cnt,
                                                  offs, counts, pairs);

    const int gemm_blocks = (N_NODES + 63) / 64;  // 1563
    gemm_in_kernel<<<gemm_blocks, 256, 0, stream>>>(x, wf_in, bi, out, hbf0);

    __hip_bfloat16* hin  = hbf0;
    __hip_bfloat16* hout = hbf1;
    for (int l = 0; l < 3; ++l) {
        const float* hl = out + (size_t)l * N_NODES * HID;
        float* hn       = out + (size_t)(l + 1) * N_NODES * HID;
        agg_gemm_kernel<<<gemm_blocks, 256, 0, stream>>>(
            hl, hin, offs, counts, (const int2*)pairs,
            wf_hid + (size_t)l * 4096, bl[l], hn, hout);
        __hip_bfloat16* t = hin; hin = hout; hout = t;
    }
}